// Round 6
// baseline (200.944 us; speedup 1.0000x reference)
//
#include <hip/hip_runtime.h>

// SpikingLinear: 40-step LIF scan over sparse one-shot input spikes.
// R6: revert snn_k inner loop to the R4 form (validated twice); R5's unroll-8
// triggered a post-timing divergence (absmax 3.0) -- suspected cross-XCD
// visibility race on prep-written metadata/WT during graph replay. Added
// __threadfence() (device-scope release) at the end of both prep_k paths as
// cheap insurance that all stores reach the coherence point before retire.
//
// Workspace layout (needs ~19.2 MB):
//   [0, 16.78MB)  WT: (IN_DIM+1) x OUT_DIM f32  (row IN_DIM = zero sentinel row)
//   [+0, 2.36MB)  ord: BATCH x ORD_STRIDE int   (byte row-offsets, bucket-sorted)
//   [+0, 42KB)    offs: BATCH x (STEPS+1) int   (padded bucket prefix offsets)

#define IN_DIM     2048
#define OUT_DIM    2048
#define BATCH      256
#define STEPS      40
#define NSLICE     32         // o-slices of 64; XCD x serves slices s%8==x (2MB/L2)
#define ORD_STRIDE 2304       // 2048 + 40*3 (pad) rounded up, 16B-aligned rows

// ---------------- fused prep: blocks [0,256) sort, [256,1280) transpose ------
__global__ __launch_bounds__(256) void prep_k(const float* __restrict__ W,
                                              float* __restrict__ WT,
                                              const float* __restrict__ inp,
                                              int* __restrict__ ord,
                                              int* __restrict__ offs) {
    __shared__ __align__(16) char smem[43008];
    const int t = threadIdx.x;

    if (blockIdx.x >= BATCH) {
        // ---- transpose W[O][IN] -> WT[IN][O] (+ zero sentinel row) ----
        float (*tile)[65] = (float (*)[65])smem;
        const int id = blockIdx.x - BATCH;
        const int bx = id & 31;          // input-dim (j) tile
        const int by = id >> 5;          // output-dim (o) tile
        const int x  = t & 63;
        const int y4 = t >> 6;           // 0..3
#pragma unroll
        for (int i = 0; i < 16; ++i) {
            const int a = y4 * 16 + i;   // o-local
            tile[a][x] = W[(size_t)(by * 64 + a) * IN_DIM + (bx * 64 + x)];
        }
        if (bx == 0 && y4 == 0)
            WT[(size_t)IN_DIM * OUT_DIM + by * 64 + x] = 0.0f;
        __syncthreads();
#pragma unroll
        for (int i = 0; i < 16; ++i) {
            const int r = y4 * 16 + i;   // j-local
            WT[(size_t)(bx * 64 + r) * OUT_DIM + (by * 64 + x)] = tile[x][r];
        }
        __threadfence();   // release: push WT stores to coherence point
        return;
    }

    // ---- deterministic stable counting sort for batch b ----
    int* hist     = (int*)smem;                    // [256][STEPS]  40960 B
    int* chunkcnt = (int*)(smem + 40960);          // [STEPS][4]      640 B
    int* binstart = (int*)(smem + 40960 + 640);    // [STEPS+1]       164 B
    int* tot      = (int*)(smem + 40960 + 640 + 164); // [STEPS]      160 B
    const int b = blockIdx.x;

    for (int i = t; i < 256 * STEPS; i += 256) hist[i] = 0;
    __syncthreads();
    int ks[8];
#pragma unroll
    for (int i = 0; i < 8; ++i) {
        const float v = inp[b * IN_DIM + t * 8 + i];   // = step * 0.5, exact
        const int k = (int)(v * 2.0f);                 // exact integer in fp32
        ks[i] = k;
        ++hist[t * STEPS + k];
    }
    __syncthreads();
    // level 1: worker (k,q) sums its 64-thread chunk of bin k (batched loads)
    if (t < STEPS * 4) {
        const int k = t >> 2, q = t & 3;
        int run = 0;
#pragma unroll
        for (int i = 0; i < 64; i += 8) {
            const int base = (q * 64 + i) * STEPS + k;
            const int c0 = hist[base + 0 * STEPS], c1 = hist[base + 1 * STEPS];
            const int c2 = hist[base + 2 * STEPS], c3 = hist[base + 3 * STEPS];
            const int c4 = hist[base + 4 * STEPS], c5 = hist[base + 5 * STEPS];
            const int c6 = hist[base + 6 * STEPS], c7 = hist[base + 7 * STEPS];
            run += ((c0 + c1) + (c2 + c3)) + ((c4 + c5) + (c6 + c7));
        }
        chunkcnt[k * 4 + q] = run;
    }
    __syncthreads();
    // level 2: tiny serial combine across 40 bins (padded to multiple of 4)
    if (t == 0) {
        int run = 0;
        for (int k = 0; k < STEPS; ++k) {
            binstart[k] = run;
            const int tk = (chunkcnt[k * 4] + chunkcnt[k * 4 + 1]) +
                           (chunkcnt[k * 4 + 2] + chunkcnt[k * 4 + 3]);
            tot[k] = tk;
            run += (tk + 3) & ~3;
        }
        binstart[STEPS] = run;
    }
    __syncthreads();
    if (t <= STEPS) offs[b * (STEPS + 1) + t] = binstart[t];
    // level 3: worker (k,q) rewrites its chunk as global exclusive prefixes
    if (t < STEPS * 4) {
        const int k = t >> 2, q = t & 3;
        int run = binstart[k];
        for (int qq = 0; qq < q; ++qq) run += chunkcnt[k * 4 + qq];
#pragma unroll 8
        for (int i = 0; i < 64; ++i) {
            const int a = (q * 64 + i) * STEPS + k;
            const int c = hist[a];
            hist[a] = run;
            run += c;
        }
    }
    __syncthreads();
    // scatter real entries (premultiplied byte row offsets), j-ascending stable
#pragma unroll
    for (int i = 0; i < 8; ++i) {
        const int k = ks[i];
        const int pos = hist[t * STEPS + k]++;
        ord[b * ORD_STRIDE + pos] = (t * 8 + i) * (OUT_DIM * 4);
    }
    // sentinel padding -> zero row (row index IN_DIM); adding 0.0f is exact
    if (t < STEPS) {
        const int beg = binstart[t] + tot[t];
        const int end = binstart[t] + ((tot[t] + 3) & ~3);
        for (int p = beg; p < end; ++p)
            ord[b * ORD_STRIDE + p] = IN_DIM * (OUT_DIM * 4);
    }
    __threadfence();   // release: push ord/offs stores to coherence point
}

// ---------------- main LIF kernel: one wave per (batch, 64-output slice) ------
__global__ __launch_bounds__(64) void snn_k(const float* __restrict__ WT,
                                            const int* __restrict__ ord,
                                            const int* __restrict__ offs,
                                            float* __restrict__ out) {
    const int wid  = blockIdx.x;
    const int s    = wid & (NSLICE - 1);   // slice; s%8 tracks XCD round-robin
    const int b    = wid >> 5;
    const int lane = threadIdx.x;
    const char* wb = (const char*)(WT + s * 64 + lane);
    const int* __restrict__ ob  = ord  + b * ORD_STRIDE;
    const int* __restrict__ off = offs + b * (STEPS + 1);

    float I = 0.f, V = 0.f;
    int   f = 0;
    int p = 0;
    for (int k = 0; k < STEPS; ++k) {
        const int e = off[k + 1];
        float a = 0.f;
        for (; p < e; p += 4) {
            const int4 jj = *(const int4*)(ob + p);   // wave-uniform
            // j-ascending order (bit-exact vs reference bucket order)
            a += *(const float*)(wb + jj.x);
            a += *(const float*)(wb + jj.y);
            a += *(const float*)(wb + jj.z);
            a += *(const float*)(wb + jj.w);
        }
        // V uses I from previous step, then I update, then spike check (ref order)
        V += 0.025f * (I - V);
        I = 0.9f * I + a;
        if (V > 1.0f) { if (f == 0) f = k; V = 0.f; }
        if (__all(f != 0)) break;
    }
    out[(size_t)b * OUT_DIM + s * 64 + lane] = f ? (float)f : 20.0f;
}

extern "C" void kernel_launch(void* const* d_in, const int* in_sizes, int n_in,
                              void* d_out, int out_size, void* d_ws, size_t ws_size,
                              hipStream_t stream) {
    const float* inp = (const float*)d_in[0];
    const float* W   = (const float*)d_in[1];
    float* out = (float*)d_out;
    char*  ws  = (char*)d_ws;

    float* WT = (float*)ws;                                   // (IN_DIM+1) rows
    const size_t WT_BYTES = (size_t)(IN_DIM + 1) * OUT_DIM * sizeof(float);
    int* ord  = (int*)(ws + WT_BYTES);
    int* offs = (int*)(ws + WT_BYTES + (size_t)BATCH * ORD_STRIDE * sizeof(int));

    prep_k<<<BATCH + (IN_DIM / 64) * (OUT_DIM / 64), 256, 0, stream>>>(W, WT, inp, ord, offs);
    snn_k<<<BATCH * NSLICE, 64, 0, stream>>>(WT, ord, offs, out);
}

// Round 7
// 70.370 us; speedup vs baseline: 2.8555x; 2.8555x over previous
//
#include <hip/hip_runtime.h>

// SpikingLinear: 40-step LIF scan over sparse one-shot input spikes.
// R7: __threadfence() (150us of per-block buffer_wbl2!) replaced by
// non-temporal stores for all prep_k outputs -- no dirty producer-L2 lines,
// so cross-XCD visibility insurance at ~zero cost. Sort hist stride 40->41
// (kills the 902K LDS bank conflicts). snn_k: per-lane early-out guard
// (spiked lanes stop loading; deterministic, output-irrelevant work only).
//
// Workspace layout (needs ~19.2 MB):
//   [0, 16.78MB)  WT: (IN_DIM+1) x OUT_DIM f32  (row IN_DIM = zero sentinel row)
//   [+0, 2.36MB)  ord: BATCH x ORD_STRIDE int   (byte row-offsets, bucket-sorted)
//   [+0, 42KB)    offs: BATCH x (STEPS+1) int   (padded bucket prefix offsets)

#define IN_DIM     2048
#define OUT_DIM    2048
#define BATCH      256
#define STEPS      40
#define NSLICE     32         // o-slices of 64; XCD x serves slices s%8==x (2MB/L2)
#define ORD_STRIDE 2304       // 2048 + 40*3 (pad) rounded up, 16B-aligned rows
#define HSTRIDE    41         // hist row stride (ints): 41 breaks 8-way conflicts

// ---------------- fused prep: blocks [0,256) sort, [256,1280) transpose ------
__global__ __launch_bounds__(256) void prep_k(const float* __restrict__ W,
                                              float* __restrict__ WT,
                                              const float* __restrict__ inp,
                                              int* __restrict__ ord,
                                              int* __restrict__ offs) {
    __shared__ __align__(16) char smem[43008];
    const int t = threadIdx.x;

    if (blockIdx.x >= BATCH) {
        // ---- transpose W[O][IN] -> WT[IN][O] (+ zero sentinel row) ----
        float (*tile)[65] = (float (*)[65])smem;
        const int id = blockIdx.x - BATCH;
        const int bx = id & 31;          // input-dim (j) tile
        const int by = id >> 5;          // output-dim (o) tile
        const int x  = t & 63;
        const int y4 = t >> 6;           // 0..3
#pragma unroll
        for (int i = 0; i < 16; ++i) {
            const int a = y4 * 16 + i;   // o-local
            tile[a][x] = W[(size_t)(by * 64 + a) * IN_DIM + (bx * 64 + x)];
        }
        if (bx == 0 && y4 == 0)
            __builtin_nontemporal_store(0.0f, &WT[(size_t)IN_DIM * OUT_DIM + by * 64 + x]);
        __syncthreads();
#pragma unroll
        for (int i = 0; i < 16; ++i) {
            const int r = y4 * 16 + i;   // j-local
            __builtin_nontemporal_store(tile[x][r],
                &WT[(size_t)(bx * 64 + r) * OUT_DIM + (by * 64 + x)]);
        }
        return;
    }

    // ---- deterministic stable counting sort for batch b ----
    int* hist     = (int*)smem;                       // [256][HSTRIDE] 41984 B
    int* chunkcnt = (int*)(smem + 41984);             // [STEPS][4]       640 B
    int* binstart = (int*)(smem + 41984 + 640);       // [STEPS+1]        164 B
    int* tot      = (int*)(smem + 41984 + 640 + 164); // [STEPS]          160 B
    const int b = blockIdx.x;

    for (int i = t; i < 256 * HSTRIDE; i += 256) hist[i] = 0;
    __syncthreads();
    int ks[8];
#pragma unroll
    for (int i = 0; i < 8; ++i) {
        const float v = inp[b * IN_DIM + t * 8 + i];   // = step * 0.5, exact
        const int k = (int)(v * 2.0f);                 // exact integer in fp32
        ks[i] = k;
        ++hist[t * HSTRIDE + k];
    }
    __syncthreads();
    // level 1: worker (k,q) sums its 64-thread chunk of bin k (batched loads)
    if (t < STEPS * 4) {
        const int k = t >> 2, q = t & 3;
        int run = 0;
#pragma unroll
        for (int i = 0; i < 64; i += 8) {
            const int base = (q * 64 + i) * HSTRIDE + k;
            const int c0 = hist[base + 0 * HSTRIDE], c1 = hist[base + 1 * HSTRIDE];
            const int c2 = hist[base + 2 * HSTRIDE], c3 = hist[base + 3 * HSTRIDE];
            const int c4 = hist[base + 4 * HSTRIDE], c5 = hist[base + 5 * HSTRIDE];
            const int c6 = hist[base + 6 * HSTRIDE], c7 = hist[base + 7 * HSTRIDE];
            run += ((c0 + c1) + (c2 + c3)) + ((c4 + c5) + (c6 + c7));
        }
        chunkcnt[k * 4 + q] = run;
    }
    __syncthreads();
    // level 2: tiny serial combine across 40 bins (padded to multiple of 4)
    if (t == 0) {
        int run = 0;
        for (int k = 0; k < STEPS; ++k) {
            binstart[k] = run;
            const int tk = (chunkcnt[k * 4] + chunkcnt[k * 4 + 1]) +
                           (chunkcnt[k * 4 + 2] + chunkcnt[k * 4 + 3]);
            tot[k] = tk;
            run += (tk + 3) & ~3;
        }
        binstart[STEPS] = run;
    }
    __syncthreads();
    if (t <= STEPS)
        __builtin_nontemporal_store(binstart[t], &offs[b * (STEPS + 1) + t]);
    // level 3: worker (k,q) rewrites its chunk as global exclusive prefixes
    if (t < STEPS * 4) {
        const int k = t >> 2, q = t & 3;
        int run = binstart[k];
        for (int qq = 0; qq < q; ++qq) run += chunkcnt[k * 4 + qq];
#pragma unroll 8
        for (int i = 0; i < 64; ++i) {
            const int a = (q * 64 + i) * HSTRIDE + k;
            const int c = hist[a];
            hist[a] = run;
            run += c;
        }
    }
    __syncthreads();
    // scatter real entries (premultiplied byte row offsets), j-ascending stable
#pragma unroll
    for (int i = 0; i < 8; ++i) {
        const int k = ks[i];
        const int pos = hist[t * HSTRIDE + k]++;
        __builtin_nontemporal_store((t * 8 + i) * (OUT_DIM * 4),
                                    &ord[b * ORD_STRIDE + pos]);
    }
    // sentinel padding -> zero row (row index IN_DIM); adding 0.0f is exact
    if (t < STEPS) {
        const int beg = binstart[t] + tot[t];
        const int end = binstart[t] + ((tot[t] + 3) & ~3);
        for (int p = beg; p < end; ++p)
            __builtin_nontemporal_store(IN_DIM * (OUT_DIM * 4),
                                        &ord[b * ORD_STRIDE + p]);
    }
}

// ---------------- main LIF kernel: one wave per (batch, 64-output slice) ------
__global__ __launch_bounds__(64) void snn_k(const float* __restrict__ WT,
                                            const int* __restrict__ ord,
                                            const int* __restrict__ offs,
                                            float* __restrict__ out) {
    const int wid  = blockIdx.x;
    const int s    = wid & (NSLICE - 1);   // slice; s%8 tracks XCD round-robin
    const int b    = wid >> 5;
    const int lane = threadIdx.x;
    const char* wb = (const char*)(WT + s * 64 + lane);
    const int* __restrict__ ob  = ord  + b * ORD_STRIDE;
    const int* __restrict__ off = offs + b * (STEPS + 1);

    float I = 0.f, V = 0.f;
    int   f = 0;
    int p = 0;
    for (int k = 0; k < STEPS; ++k) {
        const int e = off[k + 1];
        if (f == 0) {   // spiked lanes stop: their I/V/loads are output-irrelevant
            float a = 0.f;
            for (; p < e; p += 4) {
                const int4 jj = *(const int4*)(ob + p);
                // j-ascending order (bit-exact vs reference bucket order)
                a += *(const float*)(wb + jj.x);
                a += *(const float*)(wb + jj.y);
                a += *(const float*)(wb + jj.z);
                a += *(const float*)(wb + jj.w);
            }
            // V uses I from previous step, then I update, then spike (ref order)
            V += 0.025f * (I - V);
            I = 0.9f * I + a;
            if (V > 1.0f) { f = k; V = 0.f; }   // k=0 can't spike (V=0), f=0 safe
        }
        if (__all(f != 0)) break;
    }
    out[(size_t)b * OUT_DIM + s * 64 + lane] = f ? (float)f : 20.0f;
}

extern "C" void kernel_launch(void* const* d_in, const int* in_sizes, int n_in,
                              void* d_out, int out_size, void* d_ws, size_t ws_size,
                              hipStream_t stream) {
    const float* inp = (const float*)d_in[0];
    const float* W   = (const float*)d_in[1];
    float* out = (float*)d_out;
    char*  ws  = (char*)d_ws;

    float* WT = (float*)ws;                                   // (IN_DIM+1) rows
    const size_t WT_BYTES = (size_t)(IN_DIM + 1) * OUT_DIM * sizeof(float);
    int* ord  = (int*)(ws + WT_BYTES);
    int* offs = (int*)(ws + WT_BYTES + (size_t)BATCH * ORD_STRIDE * sizeof(int));

    prep_k<<<BATCH + (IN_DIM / 64) * (OUT_DIM / 64), 256, 0, stream>>>(W, WT, inp, ord, offs);
    snn_k<<<BATCH * NSLICE, 64, 0, stream>>>(WT, ord, offs, out);
}

// Round 8
// 42.951 us; speedup vs baseline: 4.6784x; 1.6384x over previous
//
#include <hip/hip_runtime.h>

// SpikingLinear: 40-step LIF scan over sparse one-shot input spikes.
// R8: self-sorting snn blocks (bucket sort lives in LDS -> no ord/offs
// globals, no cross-kernel scatter to race on), XCD-co-located transpose
// (WT columns for slice s written and read on XCD s%8, dirty-L2-local),
// and the unroll-8 load pipeline (safe now: indices come from LDS).
// Sum order = exact R4 ascending-j single-accumulator (bit-identical).
//
// Workspace: WT only: (IN_DIM+1) x OUT_DIM f32 = 16.78 MB (row 2048 = zeros).

#define IN_DIM   2048
#define OUT_DIM  2048
#define BATCH    256
#define STEPS    40
#define ROWBYTES (OUT_DIM * 4)
#define HS       41            // hist row stride (ints) -> no bank conflicts
#define ORD_CAP  2176          // 2048 + 40*3 pad, rounded to x4 (16B quads)

// ---- transpose W[O][IN] -> WT[IN][O]; o-tile 'by' on XCD by%8 (= id%8) ----
__global__ __launch_bounds__(256) void transpose_k(const float* __restrict__ W,
                                                   float* __restrict__ WT) {
    __shared__ float tile[64][65];
    const int id = blockIdx.x;
    const int by = id & 31;        // o-tile (fast-varying -> XCD = by%8)
    const int bx = id >> 5;        // j-tile
    const int x  = threadIdx.x & 63;
    const int y4 = threadIdx.x >> 6;
#pragma unroll
    for (int i = 0; i < 16; ++i) {
        const int a = y4 * 16 + i;     // o-local
        tile[a][x] = W[(size_t)(by * 64 + a) * IN_DIM + (bx * 64 + x)];
    }
    if (bx == 0 && y4 == 0)            // zero sentinel row (row IN_DIM)
        WT[(size_t)IN_DIM * OUT_DIM + by * 64 + x] = 0.0f;
    __syncthreads();
#pragma unroll
    for (int i = 0; i < 16; ++i) {
        const int r = y4 * 16 + i;     // j-local
        WT[(size_t)(bx * 64 + r) * OUT_DIM + (by * 64 + x)] = tile[x][r];
    }
}

// ---- snn: block (b, sg): sort row b in LDS, then 4 waves run slices
//      s = sg + w*8 (all on XCD sg, where transpose wrote those columns) ----
__global__ __launch_bounds__(256) void snn_k(const float* __restrict__ WT,
                                             const float* __restrict__ inp,
                                             float* __restrict__ out) {
    __shared__ __align__(16) int ordl[ORD_CAP];  // bucket-sorted byte row-offsets
    __shared__ int hist[64 * HS];
    __shared__ int bs[STEPS + 1];                // padded bucket starts
    __shared__ int tot[STEPS];                   // true bucket sizes

    const int bid = blockIdx.x;
    const int sg  = bid & 7;        // slice group == XCD (round-robin dispatch)
    const int b   = bid >> 3;
    const int t   = threadIdx.x;

    // phase 1: zero hist
    for (int i = t; i < 64 * HS; i += 256) hist[i] = 0;
    __syncthreads();

    // phase 2: threads 0..63 load row b (32 elems each) + private histogram
    int ks[32];
    if (t < 64) {
        const float* row = inp + (size_t)b * IN_DIM + t * 32;
#pragma unroll
        for (int i = 0; i < 8; ++i) {
            const float4 v = *(const float4*)(row + i * 4);  // t=step*0.5 exact
            ks[i * 4 + 0] = (int)(v.x * 2.0f);
            ks[i * 4 + 1] = (int)(v.y * 2.0f);
            ks[i * 4 + 2] = (int)(v.z * 2.0f);
            ks[i * 4 + 3] = (int)(v.w * 2.0f);
        }
#pragma unroll
        for (int i = 0; i < 32; ++i) ++hist[t * HS + ks[i]];
    }
    __syncthreads();

    // phase 3: threads 0..39: exclusive prefix over the 64 thread-rows of bin t
    if (t < STEPS) {
        int run = 0;
        for (int tt = 0; tt < 64; ++tt) {
            const int c = hist[tt * HS + t];
            hist[tt * HS + t] = run;
            run += c;
        }
        tot[t] = run;
    }
    __syncthreads();

    // phase 4: padded bucket starts (serial over 40 bins, trivial)
    if (t == 0) {
        int run = 0;
        for (int k = 0; k < STEPS; ++k) {
            bs[k] = run;
            run += (tot[k] + 3) & ~3;
        }
        bs[STEPS] = run;
    }
    __syncthreads();

    // phase 5: scatter (threads 0..63, ascending j within bin -> exact R4
    // sum order) + sentinel padding (threads 64..103, zero-row offset)
    if (t < 64) {
#pragma unroll
        for (int i = 0; i < 32; ++i) {
            const int k = ks[i];
            const int pos = bs[k] + hist[t * HS + k]++;
            ordl[pos] = (t * 32 + i) * ROWBYTES;
        }
    } else if (t < 64 + STEPS) {
        const int k = t - 64;
        for (int p2 = bs[k] + tot[k]; p2 < bs[k + 1]; ++p2)
            ordl[p2] = IN_DIM * ROWBYTES;      // +0.0f, exact
    }
    __syncthreads();

    // ---- main LIF loop: wave w handles slice s = sg + w*8 ----
    const int wave = t >> 6, lane = t & 63;
    const int s    = sg + wave * 8;
    const char* wb = (const char*)WT + ((s * 64 + lane) << 2);

    float I = 0.f, V = 0.f;
    int   f = 0;
    int   p = 0;
    for (int k = 0; k < STEPS; ++k) {
        const int e = bs[k + 1];
        float a = 0.f;
        // unroll x8: 8 row loads in flight (indices from LDS broadcast)
        for (; p + 8 <= e; p += 8) {
            const int4 ja = *(const int4*)(ordl + p);
            const int4 jb = *(const int4*)(ordl + p + 4);
            const float w0 = *(const float*)(wb + ja.x);
            const float w1 = *(const float*)(wb + ja.y);
            const float w2 = *(const float*)(wb + ja.z);
            const float w3 = *(const float*)(wb + ja.w);
            const float w4 = *(const float*)(wb + jb.x);
            const float w5 = *(const float*)(wb + jb.y);
            const float w6 = *(const float*)(wb + jb.z);
            const float w7 = *(const float*)(wb + jb.w);
            // sequential adds, ascending j: same order as validated R4 kernel
            a = (((((((((a + w0) + w1) + w2) + w3) + w4) + w5) + w6) + w7));
        }
        if (p < e) {   // exactly one remaining quad (buckets padded to x4)
            const int4 ja = *(const int4*)(ordl + p);
            p += 4;
            const float w0 = *(const float*)(wb + ja.x);
            const float w1 = *(const float*)(wb + ja.y);
            const float w2 = *(const float*)(wb + ja.z);
            const float w3 = *(const float*)(wb + ja.w);
            a = ((((a + w0) + w1) + w2) + w3);
        }
        // V uses I from previous step, then I update, then spike (ref order)
        V += 0.025f * (I - V);
        I = 0.9f * I + a;
        if (V > 1.0f) { if (f == 0) f = k; V = 0.f; }
        if (__all(f != 0)) break;    // per-wave exit, no block barrier needed
    }
    out[(size_t)b * OUT_DIM + s * 64 + lane] = f ? (float)f : 20.0f;
}

extern "C" void kernel_launch(void* const* d_in, const int* in_sizes, int n_in,
                              void* d_out, int out_size, void* d_ws, size_t ws_size,
                              hipStream_t stream) {
    const float* inp = (const float*)d_in[0];
    const float* W   = (const float*)d_in[1];
    float* out = (float*)d_out;
    float* WT  = (float*)d_ws;    // (IN_DIM+1) x OUT_DIM

    transpose_k<<<(IN_DIM / 64) * (OUT_DIM / 64), 256, 0, stream>>>(W, WT);
    snn_k<<<BATCH * 8, 256, 0, stream>>>(WT, inp, out);
}